// Round 1
// 426.472 us; speedup vs baseline: 1.1163x; 1.1163x over previous
//
#include <hip/hip_runtime.h>
#include <hip/hip_bf16.h>
#include <stdint.h>

// HydraAttention pipeline. Inputs fp32, output fp32.
//   cvt   : query, w_qkv, w_out  fp32 -> bf16
//   GEMM1 : qkv = query @ w_qkv^T + b_qkv  -> q,k,v bf16
//   attn  : per t: S = (q_hat k_hat^T)/8, softmax, ws = P v
//   GEMM2 : out = ws @ w_out^T + b_out -> fp32
//
// GEMMs: 256x256 tile, BK=64, 8 waves (2Mx4N), double-buffered 128KB LDS,
// 4 phases per K-tile with counted vmcnt(2) (never drain-0 in loop),
// st-XOR LDS swizzle (read-side XOR + inverse-swizzled global_load_lds source),
// setprio(1) around MFMA clusters, bijective XCD blockIdx swizzle.

typedef __attribute__((ext_vector_type(8))) short short8;   // 8 x bf16
typedef __attribute__((ext_vector_type(4))) float floatx4;  // MFMA C/D

__device__ __forceinline__ float bf2f(short s) {
  union { unsigned u; float f; } v;
  v.u = ((unsigned)(unsigned short)s) << 16;
  return v.f;
}
__device__ __forceinline__ short f2bf(float x) {
  union { float f; unsigned u; } v; v.f = x;
  unsigned u = v.u;
  unsigned r = (u + 0x7fffu + ((u >> 16) & 1u)) >> 16;  // RNE
  return (short)r;
}
__device__ __forceinline__ short8 pack_bf8(float4 lo, float4 hi) {
  short8 r;
  r[0] = f2bf(lo.x); r[1] = f2bf(lo.y); r[2] = f2bf(lo.z); r[3] = f2bf(lo.w);
  r[4] = f2bf(hi.x); r[5] = f2bf(hi.y); r[6] = f2bf(hi.z); r[7] = f2bf(hi.w);
  return r;
}

// Async global->LDS, 16 B per lane. LDS dest = wave-uniform base + lane*16.
__device__ __forceinline__ void gl2lds16(const short* g, short* l) {
  __builtin_amdgcn_global_load_lds(
      (const __attribute__((address_space(1))) void*)g,
      (__attribute__((address_space(3))) void*)l, 16, 0, 0);
}

// ---------------------------------------------------------------------------
// fp32 -> bf16 elementwise, 8 elems/thread. n8 = n/8.
// ---------------------------------------------------------------------------
__global__ __launch_bounds__(256)
void cvt_bf16(const float* __restrict__ in, short* __restrict__ out, int n8) {
  const int i = blockIdx.x * 256 + threadIdx.x;
  if (i < n8) {
    float4 a = ((const float4*)in)[2 * i];
    float4 b = ((const float4*)in)[2 * i + 1];
    ((short8*)out)[i] = pack_bf8(a, b);
  }
}

// ---------------------------------------------------------------------------
// Pure-bf16 GEMM (B^T form): C[m,n] = sum_k A[m,k]*W[n,k] + bias[n]
// 256x256x(BK=64) 8-wave deep-pipelined schedule (see header comment).
// EPI=0: scatter n>>10 -> {o0,o1,o2} bf16 (q/k/v). EPI=1: fp32 out w/ remap.
// ---------------------------------------------------------------------------
template <int EPI>
__global__ __launch_bounds__(512, 2)
void gemm_bf(const short* __restrict__ A, const short* __restrict__ W,
             const float* __restrict__ bias, void* __restrict__ o0,
             void* __restrict__ o1, void* __restrict__ o2, int K,
             int rowbase, int tsh) {
  // [buf][A/B][256 rows][64 k] bf16 = 128 KiB total.
  __shared__ __align__(16) short lds[2][2][16384];

  const int tid  = threadIdx.x;
  const int lane = tid & 63, wave = tid >> 6;
  const int l15  = lane & 15, quad = lane >> 4;
  const int wm   = wave >> 2, wn = wave & 3;   // 2 x 4 wave grid

  // Bijective XCD-aware block swizzle (m204 form; works for any nwg).
  const int gx   = gridDim.x;
  const int nwg  = gx * gridDim.y;
  const int orig = blockIdx.y * gx + blockIdx.x;
  const int qq = nwg >> 3, rr = nwg & 7;
  const int xcd = orig & 7, off = orig >> 3;
  const int wgid = (xcd < rr ? xcd * (qq + 1) : rr * (qq + 1) + (xcd - rr) * qq) + off;
  const int m0 = (wgid / gx) * 256, n0 = (wgid % gx) * 256;

  // --- staging geometry: per half-tile (128 rows x 64 k = 16KB) each thread
  // issues 2 x 16B. Call c covers half-local bytes (c*8192 + tid*16).
  // Linear LDS dest; SOURCE column pre-swizzled with the read-side involution
  // byte ^= ((row&7)<<4)  (both-sides-or-neither rule).
  const int rl0 = tid >> 3;                  // row within half for call 0 (0..63)
  const int ic0 = (tid & 7) << 4;            // in-row byte (0..112)
  const int sc  = ic0 ^ ((rl0 & 7) << 4);    // swizzled src col byte (call1: rl0+64 -> same &7)
  const short* Ag = A + (size_t)(m0 + rl0) * K + (sc >> 1);
  const short* Wg = W + (size_t)(n0 + rl0) * K + (sc >> 1);

  const int NT = K >> 6;   // K-tiles of 64

  auto stageA = [&](int buf, int h, int t) {
    const short* g = Ag + (size_t)(h * 128) * K + t * 64;
    short* d = &lds[buf][0][h * 8192 + tid * 8];
    gl2lds16(g, d);
    gl2lds16(g + (size_t)64 * K, d + 4096);
  };
  auto stageB = [&](int buf, int h, int t) {
    const short* g = Wg + (size_t)(h * 128) * K + t * 64;
    short* d = &lds[buf][1][h * 8192 + tid * 8];
    gl2lds16(g, d);
    gl2lds16(g + (size_t)64 * K, d + 4096);
  };

  // --- fragment read geometry (row&7 == l15&7 for all frag rows) ---
  const int xsw   = (l15 & 7) << 4;
  const int aRow  = (wm * 128 + l15) * 64;            // shorts
  const int bRow  = (wn * 64 + l15) * 64;
  const int kOff0 = (((0 * 64) + quad * 16) ^ xsw) >> 1;
  const int kOff1 = (((1 * 64) + quad * 16) ^ xsw) >> 1;

  floatx4 acc[8][4] = {};

  // Prologue: tile 0 fully, tile 1 A-half0. vmcnt(2) leaves only the latter in flight.
  stageA(0, 0, 0); stageA(0, 1, 0); stageB(0, 0, 0); stageB(0, 1, 0);
  if (NT > 1) {
    stageA(1, 0, 1);
    asm volatile("s_waitcnt vmcnt(2)" ::: "memory");
  } else {
    asm volatile("s_waitcnt vmcnt(0)" ::: "memory");
  }
  asm volatile("" ::: "memory");
  __builtin_amdgcn_s_barrier();
  asm volatile("" ::: "memory");

  short8 af[4][2], bfv[4][2];

  for (int t = 0; t < NT; ++t) {
    const int cb = t & 1;
    const short* As = lds[cb][0];
    const short* Bs = lds[cb][1];

    // ---------- q0: read A(mh=0)+B(nh=0); stage A-half1(t+1) ----------
#pragma unroll
    for (int i = 0; i < 4; ++i) {
      af[i][0] = *(const short8*)(As + aRow + i * 1024 + kOff0);
      af[i][1] = *(const short8*)(As + aRow + i * 1024 + kOff1);
    }
#pragma unroll
    for (int j = 0; j < 2; ++j) {
      bfv[j][0] = *(const short8*)(Bs + bRow + j * 1024 + kOff0);
      bfv[j][1] = *(const short8*)(Bs + bRow + j * 1024 + kOff1);
    }
    if (t + 1 < NT) stageA(cb ^ 1, 1, t + 1);
    asm volatile("" ::: "memory");
    __builtin_amdgcn_s_barrier();
    asm volatile("s_waitcnt lgkmcnt(0)" ::: "memory");
    __builtin_amdgcn_s_setprio(1);
#pragma unroll
    for (int i = 0; i < 4; ++i)
#pragma unroll
      for (int j = 0; j < 2; ++j) {
        acc[i][j] = __builtin_amdgcn_mfma_f32_16x16x32_bf16(af[i][0], bfv[j][0], acc[i][j], 0, 0, 0);
        acc[i][j] = __builtin_amdgcn_mfma_f32_16x16x32_bf16(af[i][1], bfv[j][1], acc[i][j], 0, 0, 0);
      }
    __builtin_amdgcn_s_setprio(0);
    asm volatile("" ::: "memory");
    __builtin_amdgcn_s_barrier();
    asm volatile("" ::: "memory");

    // ---------- q1: read B(nh=1); stage B-half0(t+1) ----------
#pragma unroll
    for (int j = 0; j < 2; ++j) {
      bfv[2 + j][0] = *(const short8*)(Bs + bRow + 2048 + j * 1024 + kOff0);
      bfv[2 + j][1] = *(const short8*)(Bs + bRow + 2048 + j * 1024 + kOff1);
    }
    if (t + 1 < NT) stageB(cb ^ 1, 0, t + 1);
    asm volatile("" ::: "memory");
    __builtin_amdgcn_s_barrier();
    asm volatile("s_waitcnt lgkmcnt(0)" ::: "memory");
    __builtin_amdgcn_s_setprio(1);
#pragma unroll
    for (int i = 0; i < 4; ++i)
#pragma unroll
      for (int j = 0; j < 2; ++j) {
        acc[i][2 + j] = __builtin_amdgcn_mfma_f32_16x16x32_bf16(af[i][0], bfv[2 + j][0], acc[i][2 + j], 0, 0, 0);
        acc[i][2 + j] = __builtin_amdgcn_mfma_f32_16x16x32_bf16(af[i][1], bfv[2 + j][1], acc[i][2 + j], 0, 0, 0);
      }
    __builtin_amdgcn_s_setprio(0);
    asm volatile("" ::: "memory");
    __builtin_amdgcn_s_barrier();
    asm volatile("" ::: "memory");

    // ---------- q2: read A(mh=1); stage B-half1(t+1) ----------
#pragma unroll
    for (int i = 0; i < 4; ++i) {
      af[i][0] = *(const short8*)(As + aRow + 4096 + i * 1024 + kOff0);
      af[i][1] = *(const short8*)(As + aRow + 4096 + i * 1024 + kOff1);
    }
    if (t + 1 < NT) stageB(cb ^ 1, 1, t + 1);
    asm volatile("" ::: "memory");
    __builtin_amdgcn_s_barrier();
    asm volatile("s_waitcnt lgkmcnt(0)" ::: "memory");
    __builtin_amdgcn_s_setprio(1);
#pragma unroll
    for (int i = 0; i < 4; ++i)
#pragma unroll
      for (int j = 0; j < 2; ++j) {
        acc[4 + i][j] = __builtin_amdgcn_mfma_f32_16x16x32_bf16(af[i][0], bfv[j][0], acc[4 + i][j], 0, 0, 0);
        acc[4 + i][j] = __builtin_amdgcn_mfma_f32_16x16x32_bf16(af[i][1], bfv[j][1], acc[4 + i][j], 0, 0, 0);
      }
    __builtin_amdgcn_s_setprio(0);
    asm volatile("" ::: "memory");
    __builtin_amdgcn_s_barrier();
    asm volatile("" ::: "memory");

    // ---------- q3: stage A-half0(t+2) into current buf; counted vmcnt ----------
    // Safe: all reads of this buffer retired at q2's lgkmcnt(0) + barrier.
    if (t + 2 < NT) {
      stageA(cb, 0, t + 2);
      asm volatile("s_waitcnt vmcnt(2)" ::: "memory");   // tile t+1 halves landed
    } else if (t + 1 < NT) {
      asm volatile("s_waitcnt vmcnt(0)" ::: "memory");   // last prefetched tile: drain
    }
    asm volatile("" ::: "memory");
    __builtin_amdgcn_s_barrier();
    __builtin_amdgcn_s_setprio(1);
#pragma unroll
    for (int i = 0; i < 4; ++i)
#pragma unroll
      for (int j = 0; j < 2; ++j) {
        acc[4 + i][2 + j] = __builtin_amdgcn_mfma_f32_16x16x32_bf16(af[i][0], bfv[2 + j][0], acc[4 + i][2 + j], 0, 0, 0);
        acc[4 + i][2 + j] = __builtin_amdgcn_mfma_f32_16x16x32_bf16(af[i][1], bfv[2 + j][1], acc[4 + i][2 + j], 0, 0, 0);
      }
    __builtin_amdgcn_s_setprio(0);
    asm volatile("" ::: "memory");
    __builtin_amdgcn_s_barrier();
    asm volatile("" ::: "memory");
  }

  // Epilogue. C/D layout: col = lane&15 (n), row = quad*4 + r (m).
#pragma unroll
  for (int j = 0; j < 4; ++j) {
    const int n = n0 + wn * 64 + j * 16 + l15;
    const float bv = bias[n];
    if constexpr (EPI == 0) {
      const int which = n >> 10, e = n & 1023;
      short* o = (which == 0) ? (short*)o0 : ((which == 1) ? (short*)o1 : (short*)o2);
#pragma unroll
      for (int i = 0; i < 8; ++i)
#pragma unroll
        for (int r = 0; r < 4; ++r) {
          const int mloc = m0 + wm * 128 + i * 16 + quad * 4 + r;
          o[(size_t)mloc * 1024 + e] = f2bf(acc[i][j][r] + bv);
        }
    } else {
#pragma unroll
      for (int i = 0; i < 8; ++i)
#pragma unroll
        for (int r = 0; r < 4; ++r) {
          const int mloc = m0 + wm * 128 + i * 16 + quad * 4 + r;
          const int g = ((mloc >> tsh) << 11) + rowbase + (mloc & ((1 << tsh) - 1));
          ((float*)o0)[(size_t)g * 1024 + n] = acc[i][j][r] + bv;
        }
    }
  }
}

// ---------------------------------------------------------------------------
// Attention: one block (256 thr, 4 waves) per local t'. (unchanged)
// ---------------------------------------------------------------------------
__global__ __launch_bounds__(256)
void attn_kernel(const short* __restrict__ qb, const short* __restrict__ kb,
                 const short* __restrict__ vb, short* __restrict__ wsb, int tch) {
  __shared__ __align__(16) char smem[55296];
  short* qs  = (short*)smem;             // [128][72]
  short* ks  = (short*)(smem + 18432);   // [128][72]
  short* Ps  = (short*)smem;             // [128][136] (overlays qs/ks after S)
  short* vt  = (short*)(smem + 36864);   // [64][136]
  float* rsq = (float*)(smem + 54272);   // [128]
  float* rsk = rsq + 128;                // [128]

  const int tp   = blockIdx.x;
  const int tid  = threadIdx.x;
  const int lane = tid & 63, wave = tid >> 6;
  const int l15  = lane & 15, quad = lane >> 4;
  const size_t base = (size_t)tp * 8192;

#pragma unroll
  for (int it = 0; it < 4; it++) {
    const int c = tid + it * 256;
    const int row = c >> 3, c8 = (c & 7) * 8;
    uint4 qv = *(const uint4*)(qb + base + row * 64 + c8);
    uint4 kv = *(const uint4*)(kb + base + row * 64 + c8);
    *(uint4*)(qs + row * 72 + c8) = qv;
    *(uint4*)(ks + row * 72 + c8) = kv;
    short tmp[8];
    *(uint4*)tmp = *(const uint4*)(vb + base + row * 64 + c8);
#pragma unroll
    for (int j = 0; j < 8; j++) vt[(c8 + j) * 136 + row] = tmp[j];
  }
  __syncthreads();

  if (tid < 128) {
    float s = 0.f;
    for (int j = 0; j < 64; j++) { float x = bf2f(qs[tid * 72 + j]); s += x * x; }
    rsq[tid] = rsqrtf(s);
  } else {
    const int r = tid - 128;
    float s = 0.f;
    for (int j = 0; j < 64; j++) { float x = bf2f(ks[r * 72 + j]); s += x * x; }
    rsk[r] = rsqrtf(s);
  }
  __syncthreads();

  const int wm = wave >> 1, wn = wave & 1;
  floatx4 acc[4][4] = {};
#pragma unroll
  for (int kk = 0; kk < 64; kk += 32) {
    short8 af[4], bfv[4];
#pragma unroll
    for (int i = 0; i < 4; i++)
      af[i] = *(const short8*)(qs + (wm * 64 + i * 16 + l15) * 72 + kk + quad * 8);
#pragma unroll
    for (int j = 0; j < 4; j++)
      bfv[j] = *(const short8*)(ks + (wn * 64 + j * 16 + l15) * 72 + kk + quad * 8);
#pragma unroll
    for (int i = 0; i < 4; i++)
#pragma unroll
      for (int j = 0; j < 4; j++)
        acc[i][j] = __builtin_amdgcn_mfma_f32_16x16x32_bf16(af[i], bfv[j], acc[i][j], 0, 0, 0);
  }
  __syncthreads();

#pragma unroll
  for (int i = 0; i < 4; i++)
#pragma unroll
    for (int j = 0; j < 4; j++)
#pragma unroll
      for (int r = 0; r < 4; r++) {
        const int a    = wm * 64 + i * 16 + quad * 4 + r;
        const int bcol = wn * 64 + j * 16 + l15;
        Ps[a * 136 + bcol] = f2bf(acc[i][j][r] * rsq[a] * rsk[bcol] * 0.125f);
      }
  __syncthreads();

  if (tid < 128) {
    short* rowp = Ps + tid * 136;
    float mx = -1e30f;
    for (int c = 0; c < 128; c++) mx = fmaxf(mx, bf2f(rowp[c]));
    float sum = 0.f;
    for (int c = 0; c < 128; c++) {
      float p = __expf(bf2f(rowp[c]) - mx);
      sum += p;
      rowp[c] = f2bf(p);
    }
    rsq[tid] = 1.0f / sum;
  }
  __syncthreads();

  floatx4 acc2[2][4] = {};
#pragma unroll
  for (int kb2 = 0; kb2 < 128; kb2 += 32) {
    short8 af[2], bfv[4];
#pragma unroll
    for (int ti = 0; ti < 2; ti++)
      af[ti] = *(const short8*)(Ps + (wave * 32 + ti * 16 + l15) * 136 + kb2 + quad * 8);
#pragma unroll
    for (int tj = 0; tj < 4; tj++)
      bfv[tj] = *(const short8*)(vt + (tj * 16 + l15) * 136 + kb2 + quad * 8);
#pragma unroll
    for (int ti = 0; ti < 2; ti++)
#pragma unroll
      for (int tj = 0; tj < 4; tj++)
        acc2[ti][tj] = __builtin_amdgcn_mfma_f32_16x16x32_bf16(af[ti], bfv[tj], acc2[ti][tj], 0, 0, 0);
  }

#pragma unroll
  for (int ti = 0; ti < 2; ti++)
#pragma unroll
    for (int tj = 0; tj < 4; tj++)
#pragma unroll
      for (int r = 0; r < 4; r++) {
        const int a = wave * 32 + ti * 16 + quad * 4 + r;
        const int d = tj * 16 + l15;
        const float v = acc2[ti][tj][r] * rsq[a];
        const int bz = a >> 4, h = a & 15;
        wsb[((size_t)bz * tch + tp) * 1024 + h * 64 + d] = f2bf(v);
      }
}

// ---------------------------------------------------------------------------
extern "C" void kernel_launch(void* const* d_in, const int* in_sizes, int n_in,
                              void* d_out, int out_size, void* d_ws, size_t ws_size,
                              hipStream_t stream) {
  const float* query = (const float*)d_in[0];
  // d_in[1] (key), d_in[2] (value) unused per reference semantics.
  const float* w_qkv = (const float*)d_in[3];
  const float* b_qkv = (const float*)d_in[4];
  const float* w_out = (const float*)d_in[5];
  const float* b_out = (const float*)d_in[6];
  float* out = (float*)d_out;

  // Chunk count C: footprint = 8.4MB weights + 4*(16384/C)*2048 B.
  // Cap at 64 so Mc stays a multiple of 256 (GEMM tile).
  int C = 64;
  for (int c = 1; c <= 64; c <<= 1) {
    if ((size_t)(8388608 + 134217728 / c) <= ws_size) { C = c; break; }
  }
  const int Mc  = 16384 / C;   // rows per chunk (multiple of 256)
  const int TCH = 2048 / C;    // t's per chunk
  int tsh = 0; while ((1 << tsh) < TCH) tsh++;

  short* wqkvb = (short*)d_ws;            // 3072*1024 bf16
  short* woutb = wqkvb + 3145728;         // 1024*1024 bf16
  short* qbuf  = woutb + 1048576;
  short* kbuf  = qbuf + (size_t)Mc * 1024;
  short* vbuf  = kbuf + (size_t)Mc * 1024;
  short* wsb   = vbuf + (size_t)Mc * 1024;   // overlay: bf16 query chunk, then attn out

  cvt_bf16<<<3145728 / 8 / 256, 256, 0, stream>>>(w_qkv, wqkvb, 3145728 / 8);
  cvt_bf16<<<1048576 / 8 / 256, 256, 0, stream>>>(w_out, woutb, 1048576 / 8);

  for (int c = 0; c < C; c++) {
    const int n8 = Mc * 1024 / 8;
    cvt_bf16<<<(n8 + 255) / 256, 256, 0, stream>>>(query + (size_t)c * Mc * 1024, wsb, n8);
    gemm_bf<0><<<dim3(12, Mc / 256), 512, 0, stream>>>(
        wsb, wqkvb, b_qkv, qbuf, kbuf, vbuf, 1024, 0, 0);
    attn_kernel<<<TCH, 256, 0, stream>>>(qbuf, kbuf, vbuf, wsb, TCH);
    gemm_bf<1><<<dim3(4, Mc / 256), 512, 0, stream>>>(
        wsb, woutb, b_out, out, nullptr, nullptr, 1024, c * TCH, tsh);
  }
}

// Round 4
// 396.897 us; speedup vs baseline: 1.1995x; 1.0745x over previous
//
#include <hip/hip_runtime.h>
#include <hip/hip_bf16.h>
#include <stdint.h>

// HydraAttention pipeline. Inputs fp32, output fp32.
//   cvt   : query, w_qkv, w_out  fp32 -> bf16
//   GEMM1 : qkv = query @ w_qkv^T + b_qkv  -> q,k,v bf16
//   attn  : per t: S = (q_hat k_hat^T)/8, softmax, ws = P v
//   GEMM2 : out = ws @ w_out^T + b_out -> fp32
//
// GEMMs: 256x256 tile, BK=64, 8 waves (2Mx4N), double-buffered 128KB LDS,
// 8-phase schedule over 2 K-tiles, one half-tile stage per phase, counted
// vmcnt(4) at phases 4 & 8 only.
//
// RACE-FIX (round 4): stage placement must respect the READ geometry, which
// is per-wave (wave wm reads A rows wm*128+{0..63} at p1/p5 and wm*128+
// {64..127} at p3/p7 — i.e. EACH stage-half A-h0/A-h1 is read across TWO
// phases). A region may be staged only in a phase strictly after its last
// read's trailing barrier. Placement: p1:A1h1(o) p2:B1h1(o) p3:B0h0(e)
// p4:A0h0(e)+vmcnt(4) p5:A0h1(e) p6:B0h1(e) p7:B1h0(o') p8:A1h0(o')+vmcnt(4)
// with o=2it+1, e=2it+2, o'=2it+3. vmcnt(4)@p4 retires tile o fully before
// p5 reads it; vmcnt(4)@p8 retires tile e fully before next p1.
// Rule-18: sched_barrier(0) after every inline-asm s_waitcnt.

typedef __attribute__((ext_vector_type(8))) short short8;   // 8 x bf16
typedef __attribute__((ext_vector_type(4))) float floatx4;  // MFMA C/D

__device__ __forceinline__ float bf2f(short s) {
  union { unsigned u; float f; } v;
  v.u = ((unsigned)(unsigned short)s) << 16;
  return v.f;
}
__device__ __forceinline__ short f2bf(float x) {
  union { float f; unsigned u; } v; v.f = x;
  unsigned u = v.u;
  unsigned r = (u + 0x7fffu + ((u >> 16) & 1u)) >> 16;  // RNE
  return (short)r;
}
__device__ __forceinline__ short8 pack_bf8(float4 lo, float4 hi) {
  short8 r;
  r[0] = f2bf(lo.x); r[1] = f2bf(lo.y); r[2] = f2bf(lo.z); r[3] = f2bf(lo.w);
  r[4] = f2bf(hi.x); r[5] = f2bf(hi.y); r[6] = f2bf(hi.z); r[7] = f2bf(hi.w);
  return r;
}

// Async global->LDS, 16 B per lane. LDS dest = wave-uniform base + lane*16.
__device__ __forceinline__ void gl2lds16(const short* g, short* l) {
  __builtin_amdgcn_global_load_lds(
      (const __attribute__((address_space(1))) void*)g,
      (__attribute__((address_space(3))) void*)l, 16, 0, 0);
}

// ---------------------------------------------------------------------------
// fp32 -> bf16 elementwise, 8 elems/thread. n8 = n/8.
// ---------------------------------------------------------------------------
__global__ __launch_bounds__(256)
void cvt_bf16(const float* __restrict__ in, short* __restrict__ out, int n8) {
  const int i = blockIdx.x * 256 + threadIdx.x;
  if (i < n8) {
    float4 a = ((const float4*)in)[2 * i];
    float4 b = ((const float4*)in)[2 * i + 1];
    ((short8*)out)[i] = pack_bf8(a, b);
  }
}

// ---------------------------------------------------------------------------
// Pure-bf16 GEMM (B^T form): C[m,n] = sum_k A[m,k]*W[n,k] + bias[n]
// EPI=0: scatter n>>10 -> {o0,o1,o2} bf16 (q/k/v). EPI=1: fp32 out w/ remap.
// Requires K % 128 == 0 (NT even).
// ---------------------------------------------------------------------------

// MFMA quadrant: k-slice OUTER so consecutive MFMAs hit different accumulators.
#define DO_MFMA(BI, BJ)                                                      \
  __builtin_amdgcn_s_setprio(1);                                             \
  _Pragma("unroll")                                                          \
  for (int k = 0; k < 2; ++k)                                                \
    _Pragma("unroll")                                                        \
    for (int i = 0; i < 4; ++i)                                              \
      _Pragma("unroll")                                                      \
      for (int j = 0; j < 2; ++j)                                            \
        acc[(BI) + i][(BJ) + j] = __builtin_amdgcn_mfma_f32_16x16x32_bf16(   \
            af[i][k], bfv[(BJ) + j][k], acc[(BI) + i][(BJ) + j], 0, 0, 0);   \
  __builtin_amdgcn_s_setprio(0);

#define READ_A(SRC, MH)                                                      \
  _Pragma("unroll")                                                          \
  for (int i = 0; i < 4; ++i) {                                              \
    af[i][0] = *(const short8*)((SRC) + aRow + (MH) * 4096 + i * 1024 + kOff0); \
    af[i][1] = *(const short8*)((SRC) + aRow + (MH) * 4096 + i * 1024 + kOff1); \
  }

#define READ_B(SRC, NH)                                                      \
  _Pragma("unroll")                                                          \
  for (int j = 0; j < 2; ++j) {                                              \
    bfv[(NH) * 2 + j][0] = *(const short8*)((SRC) + bRow + (NH) * 2048 + j * 1024 + kOff0); \
    bfv[(NH) * 2 + j][1] = *(const short8*)((SRC) + bRow + (NH) * 2048 + j * 1024 + kOff1); \
  }

#define FENCE asm volatile("" ::: "memory")
// barrier, then wait own-wave ds_reads, then PIN the region (rule 18).
#define BAR_LGK                                                              \
  FENCE; __builtin_amdgcn_s_barrier();                                       \
  asm volatile("s_waitcnt lgkmcnt(0)" ::: "memory");                         \
  __builtin_amdgcn_sched_barrier(0)
#define BAR_END FENCE; __builtin_amdgcn_s_barrier(); FENCE
#define WAIT_VM(N)                                                           \
  asm volatile("s_waitcnt vmcnt(" #N ")" ::: "memory");                      \
  __builtin_amdgcn_sched_barrier(0)

template <int EPI>
__global__ __launch_bounds__(512, 2)
void gemm_bf(const short* __restrict__ A, const short* __restrict__ W,
             const float* __restrict__ bias, void* __restrict__ o0,
             void* __restrict__ o1, void* __restrict__ o2, int K,
             int rowbase, int tsh) {
  // [buf][A/B][256 rows][64 k] bf16 = 128 KiB total.
  __shared__ __align__(16) short lds[2][2][16384];

  const int tid  = threadIdx.x;
  const int lane = tid & 63, wave = tid >> 6;
  const int l15  = lane & 15, quad = lane >> 4;
  const int wm   = wave >> 2, wn = wave & 3;   // 2 x 4 wave grid

  // Bijective XCD-aware block swizzle (m204 form; works for any nwg).
  const int gx   = gridDim.x;
  const int nwg  = gx * gridDim.y;
  const int orig = blockIdx.y * gx + blockIdx.x;
  const int qq = nwg >> 3, rr = nwg & 7;
  const int xcd = orig & 7, off = orig >> 3;
  const int wgid = (xcd < rr ? xcd * (qq + 1) : rr * (qq + 1) + (xcd - rr) * qq) + off;
  const int m0 = (wgid / gx) * 256, n0 = (wgid % gx) * 256;

  // --- staging geometry: per half-tile (128 rows x 64 k = 16KB) each thread
  // issues 2 x 16B. Linear LDS dest; SOURCE column pre-swizzled with the
  // read-side involution byte ^= ((row&7)<<4).
  const int rl0 = tid >> 3;                  // row within half for call 0 (0..63)
  const int ic0 = (tid & 7) << 4;            // in-row byte (0..112)
  const int sc  = ic0 ^ ((rl0 & 7) << 4);    // swizzled src col byte
  const short* Ag = A + (size_t)(m0 + rl0) * K + (sc >> 1);
  const short* Wg = W + (size_t)(n0 + rl0) * K + (sc >> 1);

  const int NT = K >> 6;   // K-tiles of 64 (must be even)

  auto stageA = [&](int buf, int h, int t) {
    const short* g = Ag + (size_t)(h * 128) * K + t * 64;
    short* d = &lds[buf][0][h * 8192 + tid * 8];
    gl2lds16(g, d);
    gl2lds16(g + (size_t)64 * K, d + 4096);
  };
  auto stageB = [&](int buf, int h, int t) {
    const short* g = Wg + (size_t)(h * 128) * K + t * 64;
    short* d = &lds[buf][1][h * 8192 + tid * 8];
    gl2lds16(g, d);
    gl2lds16(g + (size_t)64 * K, d + 4096);
  };

  // --- fragment read geometry (row&7 == l15&7 for all frag rows) ---
  const int xsw   = (l15 & 7) << 4;
  const int aRow  = (wm * 128 + l15) * 64;            // shorts
  const int bRow  = (wn * 64 + l15) * 64;
  const int kOff0 = ((quad * 16) ^ xsw) >> 1;
  const int kOff1 = ((64 + quad * 16) ^ xsw) >> 1;

  floatx4 acc[8][4] = {};

  // Prologue: tile 0 fully -> buf0; B-h0(1), A-h0(1) -> buf1 (12 loads).
  // vmcnt(4): tile 0's 8 loads retired; tile 1's 4 may remain in flight.
  stageA(0, 0, 0); stageA(0, 1, 0); stageB(0, 0, 0); stageB(0, 1, 0);
  stageB(1, 0, 1); stageA(1, 0, 1);
  WAIT_VM(4);
  BAR_END;

  short8 af[4][2], bfv[4][2];
  const short* const A0 = lds[0][0]; const short* const B0 = lds[0][1];
  const short* const A1 = lds[1][0]; const short* const B1 = lds[1][1];

  const int NI = NT >> 1;
  for (int it = 0; it < NI; ++it) {
    const bool st = (it + 1 < NI);      // tiles 2it+2 / 2it+3 exist
    const int to = 2 * it + 1, ta = 2 * it + 2, tb = 2 * it + 3;

    // p1: read buf0 A(rows wm*128+0..63) + B(first 32 of each wave span);
    //     stage A-h1(to)->buf1  [old buf1 A-h1 last read at p5/p7 of it-1]
    READ_A(A0, 0); READ_B(B0, 0);
    stageA(1, 1, to);
    BAR_LGK;
    DO_MFMA(0, 0);
    BAR_END;

    // p2: read buf0 B(second 32 of span); stage B-h1(to)->buf1
    READ_B(B0, 1);
    stageB(1, 1, to);
    BAR_LGK;
    DO_MFMA(0, 2);
    BAR_END;

    // p3: read buf0 A(rows wm*128+64..127); stage B-h0(ta)->buf0
    //     [buf0 B fully read by p2's trailing barrier]
    READ_A(A0, 1);
    if (st) stageB(0, 0, ta);
    BAR_LGK;
    DO_MFMA(4, 0);
    BAR_END;

    // p4: no reads; stage A-h0(ta)->buf0 [buf0 A fully read by p3's barrier];
    //     wait tile to complete: vmcnt(4) retires {B1h0,A1h0,A1h1,B1h1}(to),
    //     leaves {B0h0,A0h0}(ta) in flight.
    if (st) stageA(0, 0, ta);
    DO_MFMA(4, 2);
    if (st) { WAIT_VM(4); }
    else    { WAIT_VM(0); }
    BAR_END;

    // p5: read buf1 A(rows wm*128+0..63) + B(first 32); stage A-h1(ta)->buf0
    READ_A(A1, 0); READ_B(B1, 0);
    if (st) stageA(0, 1, ta);
    BAR_LGK;
    DO_MFMA(0, 0);
    BAR_END;

    // p6: read buf1 B(second 32); stage B-h1(ta)->buf0
    READ_B(B1, 1);
    if (st) stageB(0, 1, ta);
    BAR_LGK;
    DO_MFMA(0, 2);
    BAR_END;

    // p7: read buf1 A(rows wm*128+64..127); stage B-h0(tb)->buf1
    //     [buf1 B fully read by p6's barrier]
    READ_A(A1, 1);
    if (st) stageB(1, 0, tb);
    BAR_LGK;
    DO_MFMA(4, 0);
    BAR_END;

    // p8: no reads; stage A-h0(tb)->buf1 [buf1 A fully read by p7's barrier];
    //     wait tile ta complete: vmcnt(4) retires {B0h0,A0h0,A0h1,B0h1}(ta),
    //     leaves {B1h0,A1h0}(tb) in flight.
    if (st) stageA(1, 0, tb);
    DO_MFMA(4, 2);
    if (st) { WAIT_VM(4); }
    BAR_END;
  }

  // Epilogue. C/D layout: col = lane&15 (n), row = quad*4 + r (m).
  // Row-grouped store order: per row, all 4 column-chunks back-to-back.
  if constexpr (EPI == 0) {
    float bv[4]; int ee[4]; short* op[4];
#pragma unroll
    for (int j = 0; j < 4; ++j) {
      const int n = n0 + wn * 64 + j * 16 + l15;
      bv[j] = bias[n];
      const int which = n >> 10;
      ee[j] = n & 1023;
      op[j] = (which == 0) ? (short*)o0 : ((which == 1) ? (short*)o1 : (short*)o2);
    }
#pragma unroll
    for (int i = 0; i < 8; ++i)
#pragma unroll
      for (int r = 0; r < 4; ++r) {
        const int mloc = m0 + wm * 128 + i * 16 + quad * 4 + r;
        const size_t rowoff = (size_t)mloc * 1024;
#pragma unroll
        for (int j = 0; j < 4; ++j)
          op[j][rowoff + ee[j]] = f2bf(acc[i][j][r] + bv[j]);
      }
  } else {
    float bv[4]; int nn[4];
#pragma unroll
    for (int j = 0; j < 4; ++j) {
      nn[j] = n0 + wn * 64 + j * 16 + l15;
      bv[j] = bias[nn[j]];
    }
#pragma unroll
    for (int i = 0; i < 8; ++i)
#pragma unroll
      for (int r = 0; r < 4; ++r) {
        const int mloc = m0 + wm * 128 + i * 16 + quad * 4 + r;
        const int g = ((mloc >> tsh) << 11) + rowbase + (mloc & ((1 << tsh) - 1));
        const size_t rowoff = (size_t)g * 1024;
#pragma unroll
        for (int j = 0; j < 4; ++j)
          ((float*)o0)[rowoff + nn[j]] = acc[i][j][r] + bv[j];
      }
  }
}

// ---------------------------------------------------------------------------
// Attention: one block (256 thr, 4 waves) per local t'. (unchanged)
// ---------------------------------------------------------------------------
__global__ __launch_bounds__(256)
void attn_kernel(const short* __restrict__ qb, const short* __restrict__ kb,
                 const short* __restrict__ vb, short* __restrict__ wsb, int tch) {
  __shared__ __align__(16) char smem[55296];
  short* qs  = (short*)smem;             // [128][72]
  short* ks  = (short*)(smem + 18432);   // [128][72]
  short* Ps  = (short*)smem;             // [128][136] (overlays qs/ks after S)
  short* vt  = (short*)(smem + 36864);   // [64][136]
  float* rsq = (float*)(smem + 54272);   // [128]
  float* rsk = rsq + 128;                // [128]

  const int tp   = blockIdx.x;
  const int tid  = threadIdx.x;
  const int lane = tid & 63, wave = tid >> 6;
  const int l15  = lane & 15, quad = lane >> 4;
  const size_t base = (size_t)tp * 8192;

#pragma unroll
  for (int it = 0; it < 4; it++) {
    const int c = tid + it * 256;
    const int row = c >> 3, c8 = (c & 7) * 8;
    uint4 qv = *(const uint4*)(qb + base + row * 64 + c8);
    uint4 kv = *(const uint4*)(kb + base + row * 64 + c8);
    *(uint4*)(qs + row * 72 + c8) = qv;
    *(uint4*)(ks + row * 72 + c8) = kv;
    short tmp[8];
    *(uint4*)tmp = *(const uint4*)(vb + base + row * 64 + c8);
#pragma unroll
    for (int j = 0; j < 8; j++) vt[(c8 + j) * 136 + row] = tmp[j];
  }
  __syncthreads();

  if (tid < 128) {
    float s = 0.f;
    for (int j = 0; j < 64; j++) { float x = bf2f(qs[tid * 72 + j]); s += x * x; }
    rsq[tid] = rsqrtf(s);
  } else {
    const int r = tid - 128;
    float s = 0.f;
    for (int j = 0; j < 64; j++) { float x = bf2f(ks[r * 72 + j]); s += x * x; }
    rsk[r] = rsqrtf(s);
  }
  __syncthreads();

  const int wm = wave >> 1, wn = wave & 1;
  floatx4 acc[4][4] = {};
#pragma unroll
  for (int kk = 0; kk < 64; kk += 32) {
    short8 af[4], bfv[4];
#pragma unroll
    for (int i = 0; i < 4; i++)
      af[i] = *(const short8*)(qs + (wm * 64 + i * 16 + l15) * 72 + kk + quad * 8);
#pragma unroll
    for (int j = 0; j < 4; j++)
      bfv[j] = *(const short8*)(ks + (wn * 64 + j * 16 + l15) * 72 + kk + quad * 8);
#pragma unroll
    for (int i = 0; i < 4; i++)
#pragma unroll
      for (int j = 0; j < 4; j++)
        acc[i][j] = __builtin_amdgcn_mfma_f32_16x16x32_bf16(af[i], bfv[j], acc[i][j], 0, 0, 0);
  }
  __syncthreads();

#pragma unroll
  for (int i = 0; i < 4; i++)
#pragma unroll
    for (int j = 0; j < 4; j++)
#pragma unroll
      for (int r = 0; r < 4; r++) {
        const int a    = wm * 64 + i * 16 + quad * 4 + r;
        const int bcol = wn * 64 + j * 16 + l15;
        Ps[a * 136 + bcol] = f2bf(acc[i][j][r] * rsq[a] * rsk[bcol] * 0.125f);
      }
  __syncthreads();

  if (tid < 128) {
    short* rowp = Ps + tid * 136;
    float mx = -1e30f;
    for (int c = 0; c < 128; c++) mx = fmaxf(mx, bf2f(rowp[c]));
    float sum = 0.f;
    for (int c = 0; c < 128; c++) {
      float p = __expf(bf2f(rowp[c]) - mx);
      sum += p;
      rowp[c] = f2bf(p);
    }
    rsq[tid] = 1.0f / sum;
  }
  __syncthreads();

  floatx4 acc2[2][4] = {};
#pragma unroll
  for (int kb2 = 0; kb2 < 128; kb2 += 32) {
    short8 af[2], bfv[4];
#pragma unroll
    for (int ti = 0; ti < 2; ti++)
      af[ti] = *(const short8*)(Ps + (wave * 32 + ti * 16 + l15) * 136 + kb2 + quad * 8);
#pragma unroll
    for (int tj = 0; tj < 4; tj++)
      bfv[tj] = *(const short8*)(vt + (tj * 16 + l15) * 136 + kb2 + quad * 8);
#pragma unroll
    for (int ti = 0; ti < 2; ti++)
#pragma unroll
      for (int tj = 0; tj < 4; tj++)
        acc2[ti][tj] = __builtin_amdgcn_mfma_f32_16x16x32_bf16(af[ti], bfv[tj], acc2[ti][tj], 0, 0, 0);
  }

#pragma unroll
  for (int ti = 0; ti < 2; ti++)
#pragma unroll
    for (int tj = 0; tj < 4; tj++)
#pragma unroll
      for (int r = 0; r < 4; r++) {
        const int a = wave * 32 + ti * 16 + quad * 4 + r;
        const int d = tj * 16 + l15;
        const float v = acc2[ti][tj][r] * rsq[a];
        const int bz = a >> 4, h = a & 15;
        wsb[((size_t)bz * tch + tp) * 1024 + h * 64 + d] = f2bf(v);
      }
}

// ---------------------------------------------------------------------------
extern "C" void kernel_launch(void* const* d_in, const int* in_sizes, int n_in,
                              void* d_out, int out_size, void* d_ws, size_t ws_size,
                              hipStream_t stream) {
  const float* query = (const float*)d_in[0];
  // d_in[1] (key), d_in[2] (value) unused per reference semantics.
  const float* w_qkv = (const float*)d_in[3];
  const float* b_qkv = (const float*)d_in[4];
  const float* w_out = (const float*)d_in[5];
  const float* b_out = (const float*)d_in[6];
  float* out = (float*)d_out;

  // Chunk count C: footprint = 8.4MB weights + 4*(16384/C)*2048 B.
  // Cap at 64 so Mc stays a multiple of 256 (GEMM tile).
  int C = 64;
  for (int c = 1; c <= 64; c <<= 1) {
    if ((size_t)(8388608 + 134217728 / c) <= ws_size) { C = c; break; }
  }
  const int Mc  = 16384 / C;   // rows per chunk (multiple of 256)
  const int TCH = 2048 / C;    // t's per chunk
  int tsh = 0; while ((1 << tsh) < TCH) tsh++;

  short* wqkvb = (short*)d_ws;            // 3072*1024 bf16
  short* woutb = wqkvb + 3145728;         // 1024*1024 bf16
  short* qbuf  = woutb + 1048576;
  short* kbuf  = qbuf + (size_t)Mc * 1024;
  short* vbuf  = kbuf + (size_t)Mc * 1024;
  short* wsb   = vbuf + (size_t)Mc * 1024;   // overlay: bf16 query chunk, then attn out

  cvt_bf16<<<3145728 / 8 / 256, 256, 0, stream>>>(w_qkv, wqkvb, 3145728 / 8);
  cvt_bf16<<<1048576 / 8 / 256, 256, 0, stream>>>(w_out, woutb, 1048576 / 8);

  for (int c = 0; c < C; c++) {
    const int n8 = Mc * 1024 / 8;
    cvt_bf16<<<(n8 + 255) / 256, 256, 0, stream>>>(query + (size_t)c * Mc * 1024, wsb, n8);
    gemm_bf<0><<<dim3(12, Mc / 256), 512, 0, stream>>>(
        wsb, wqkvb, b_qkv, qbuf, kbuf, vbuf, 1024, 0, 0);
    attn_kernel<<<TCH, 256, 0, stream>>>(qbuf, kbuf, vbuf, wsb, TCH);
    gemm_bf<1><<<dim3(4, Mc / 256), 512, 0, stream>>>(
        wsb, woutb, b_out, out, nullptr, nullptr, 1024, c * TCH, tsh);
  }
}

// Round 5
// 358.196 us; speedup vs baseline: 1.3291x; 1.1080x over previous
//
#include <hip/hip_runtime.h>
#include <hip/hip_bf16.h>
#include <stdint.h>

// HydraAttention pipeline. Inputs fp32, output fp32.
//   cvt   : query, w_qkv, w_out  fp32 -> bf16
//   GEMM1 : qkv = query @ w_qkv^T + b_qkv  -> q,k,v bf16
//   attn  : per t: S = (q_hat k_hat^T)/8, softmax, ws = P v
//   GEMM2 : out = ws @ w_out^T + b_out -> fp32
//
// GEMMs: 256x256 tile, BK=64, 8 waves (2Mx4N), double-buffered 128KB LDS,
// 8-phase schedule over 2 K-tiles, one half-tile stage per phase, counted
// vmcnt(4) at phases 4 & 8 only. Stage placement respects per-wave read
// geometry (see round-4 comment). R5: per-phase lgkmcnt(0)+sched_barrier
// REMOVED — fragment ds_reads are compiler-visible loads, so the compiler
// emits fine-grained lgkmcnt interleaved with MFMAs (m97/m141 evidence:
// explicit full drain + order-pinning serializes read-drain vs MFMA and
// cost ~20% MfmaUtil). vmcnt waits keep sched_barrier (staging hazard).

typedef __attribute__((ext_vector_type(8))) short short8;   // 8 x bf16
typedef __attribute__((ext_vector_type(4))) float floatx4;  // MFMA C/D

__device__ __forceinline__ float bf2f(short s) {
  union { unsigned u; float f; } v;
  v.u = ((unsigned)(unsigned short)s) << 16;
  return v.f;
}
__device__ __forceinline__ short f2bf(float x) {
  union { float f; unsigned u; } v; v.f = x;
  unsigned u = v.u;
  unsigned r = (u + 0x7fffu + ((u >> 16) & 1u)) >> 16;  // RNE
  return (short)r;
}
__device__ __forceinline__ short8 pack_bf8(float4 lo, float4 hi) {
  short8 r;
  r[0] = f2bf(lo.x); r[1] = f2bf(lo.y); r[2] = f2bf(lo.z); r[3] = f2bf(lo.w);
  r[4] = f2bf(hi.x); r[5] = f2bf(hi.y); r[6] = f2bf(hi.z); r[7] = f2bf(hi.w);
  return r;
}

// Async global->LDS, 16 B per lane. LDS dest = wave-uniform base + lane*16.
__device__ __forceinline__ void gl2lds16(const short* g, short* l) {
  __builtin_amdgcn_global_load_lds(
      (const __attribute__((address_space(1))) void*)g,
      (__attribute__((address_space(3))) void*)l, 16, 0, 0);
}

// ---------------------------------------------------------------------------
// fp32 -> bf16 elementwise, 8 elems/thread. n8 = n/8.
// ---------------------------------------------------------------------------
__global__ __launch_bounds__(256)
void cvt_bf16(const float* __restrict__ in, short* __restrict__ out, int n8) {
  const int i = blockIdx.x * 256 + threadIdx.x;
  if (i < n8) {
    float4 a = ((const float4*)in)[2 * i];
    float4 b = ((const float4*)in)[2 * i + 1];
    ((short8*)out)[i] = pack_bf8(a, b);
  }
}

// ---------------------------------------------------------------------------
// Pure-bf16 GEMM (B^T form): C[m,n] = sum_k A[m,k]*W[n,k] + bias[n]
// EPI=0: scatter n>>10 -> {o0,o1,o2} bf16 (q/k/v). EPI=1: fp32 out w/ remap.
// Requires K % 128 == 0 (NT even).
// ---------------------------------------------------------------------------

// MFMA quadrant: k-slice OUTER so consecutive MFMAs hit different accumulators.
#define DO_MFMA(BI, BJ)                                                      \
  __builtin_amdgcn_s_setprio(1);                                             \
  _Pragma("unroll")                                                          \
  for (int k = 0; k < 2; ++k)                                                \
    _Pragma("unroll")                                                        \
    for (int i = 0; i < 4; ++i)                                              \
      _Pragma("unroll")                                                      \
      for (int j = 0; j < 2; ++j)                                            \
        acc[(BI) + i][(BJ) + j] = __builtin_amdgcn_mfma_f32_16x16x32_bf16(   \
            af[i][k], bfv[(BJ) + j][k], acc[(BI) + i][(BJ) + j], 0, 0, 0);   \
  __builtin_amdgcn_s_setprio(0);

#define READ_A(SRC, MH)                                                      \
  _Pragma("unroll")                                                          \
  for (int i = 0; i < 4; ++i) {                                              \
    af[i][0] = *(const short8*)((SRC) + aRow + (MH) * 4096 + i * 1024 + kOff0); \
    af[i][1] = *(const short8*)((SRC) + aRow + (MH) * 4096 + i * 1024 + kOff1); \
  }

#define READ_B(SRC, NH)                                                      \
  _Pragma("unroll")                                                          \
  for (int j = 0; j < 2; ++j) {                                              \
    bfv[(NH) * 2 + j][0] = *(const short8*)((SRC) + bRow + (NH) * 2048 + j * 1024 + kOff0); \
    bfv[(NH) * 2 + j][1] = *(const short8*)((SRC) + bRow + (NH) * 2048 + j * 1024 + kOff1); \
  }

#define FENCE asm volatile("" ::: "memory")
// Leading barrier only: compiler tracks ds_read->MFMA deps and inserts
// fine-grained lgkmcnt interleaved with the MFMA cluster (do NOT pin).
#define BAR_LGK FENCE; __builtin_amdgcn_s_barrier(); FENCE
#define BAR_END FENCE; __builtin_amdgcn_s_barrier(); FENCE
#define WAIT_VM(N)                                                           \
  asm volatile("s_waitcnt vmcnt(" #N ")" ::: "memory");                      \
  __builtin_amdgcn_sched_barrier(0)

template <int EPI>
__global__ __launch_bounds__(512, 2)
void gemm_bf(const short* __restrict__ A, const short* __restrict__ W,
             const float* __restrict__ bias, void* __restrict__ o0,
             void* __restrict__ o1, void* __restrict__ o2, int K,
             int rowbase, int tsh) {
  // [buf][A/B][256 rows][64 k] bf16 = 128 KiB total.
  __shared__ __align__(16) short lds[2][2][16384];

  const int tid  = threadIdx.x;
  const int lane = tid & 63, wave = tid >> 6;
  const int l15  = lane & 15, quad = lane >> 4;
  const int wm   = wave >> 2, wn = wave & 3;   // 2 x 4 wave grid

  // Bijective XCD-aware block swizzle (m204 form; works for any nwg).
  const int gx   = gridDim.x;
  const int nwg  = gx * gridDim.y;
  const int orig = blockIdx.y * gx + blockIdx.x;
  const int qq = nwg >> 3, rr = nwg & 7;
  const int xcd = orig & 7, off = orig >> 3;
  const int wgid = (xcd < rr ? xcd * (qq + 1) : rr * (qq + 1) + (xcd - rr) * qq) + off;
  const int m0 = (wgid / gx) * 256, n0 = (wgid % gx) * 256;

  // --- staging geometry: per half-tile (128 rows x 64 k = 16KB) each thread
  // issues 2 x 16B. Linear LDS dest; SOURCE column pre-swizzled with the
  // read-side involution byte ^= ((row&7)<<4).
  const int rl0 = tid >> 3;                  // row within half for call 0 (0..63)
  const int ic0 = (tid & 7) << 4;            // in-row byte (0..112)
  const int sc  = ic0 ^ ((rl0 & 7) << 4);    // swizzled src col byte
  const short* Ag = A + (size_t)(m0 + rl0) * K + (sc >> 1);
  const short* Wg = W + (size_t)(n0 + rl0) * K + (sc >> 1);

  const int NT = K >> 6;   // K-tiles of 64 (must be even)

  auto stageA = [&](int buf, int h, int t) {
    const short* g = Ag + (size_t)(h * 128) * K + t * 64;
    short* d = &lds[buf][0][h * 8192 + tid * 8];
    gl2lds16(g, d);
    gl2lds16(g + (size_t)64 * K, d + 4096);
  };
  auto stageB = [&](int buf, int h, int t) {
    const short* g = Wg + (size_t)(h * 128) * K + t * 64;
    short* d = &lds[buf][1][h * 8192 + tid * 8];
    gl2lds16(g, d);
    gl2lds16(g + (size_t)64 * K, d + 4096);
  };

  // --- fragment read geometry (row&7 == l15&7 for all frag rows) ---
  const int xsw   = (l15 & 7) << 4;
  const int aRow  = (wm * 128 + l15) * 64;            // shorts
  const int bRow  = (wn * 64 + l15) * 64;
  const int kOff0 = ((quad * 16) ^ xsw) >> 1;
  const int kOff1 = ((64 + quad * 16) ^ xsw) >> 1;

  floatx4 acc[8][4] = {};

  // Prologue: tile 0 fully -> buf0; B-h0(1), A-h0(1) -> buf1 (12 loads).
  // vmcnt(4): tile 0's 8 loads retired; tile 1's 4 may remain in flight.
  stageA(0, 0, 0); stageA(0, 1, 0); stageB(0, 0, 0); stageB(0, 1, 0);
  stageB(1, 0, 1); stageA(1, 0, 1);
  WAIT_VM(4);
  BAR_END;

  short8 af[4][2], bfv[4][2];
  const short* const A0 = lds[0][0]; const short* const B0 = lds[0][1];
  const short* const A1 = lds[1][0]; const short* const B1 = lds[1][1];

  const int NI = NT >> 1;
  for (int it = 0; it < NI; ++it) {
    const bool st = (it + 1 < NI);      // tiles 2it+2 / 2it+3 exist
    const int to = 2 * it + 1, ta = 2 * it + 2, tb = 2 * it + 3;

    // p1: read buf0 A(rows wm*128+0..63) + B(first 32 of each wave span);
    //     stage A-h1(to)->buf1  [old buf1 A-h1 last read at p5/p7 of it-1]
    READ_A(A0, 0); READ_B(B0, 0);
    stageA(1, 1, to);
    BAR_LGK;
    DO_MFMA(0, 0);
    BAR_END;

    // p2: read buf0 B(second 32 of span); stage B-h1(to)->buf1
    READ_B(B0, 1);
    stageB(1, 1, to);
    BAR_LGK;
    DO_MFMA(0, 2);
    BAR_END;

    // p3: read buf0 A(rows wm*128+64..127); stage B-h0(ta)->buf0
    //     [buf0 B fully read by p2's trailing barrier]
    READ_A(A0, 1);
    if (st) stageB(0, 0, ta);
    BAR_LGK;
    DO_MFMA(4, 0);
    BAR_END;

    // p4: no reads; stage A-h0(ta)->buf0 [buf0 A fully read by p3's barrier];
    //     wait tile to complete: vmcnt(4) retires {B1h0,A1h0,A1h1,B1h1}(to),
    //     leaves {B0h0,A0h0}(ta) in flight.
    if (st) stageA(0, 0, ta);
    DO_MFMA(4, 2);
    if (st) { WAIT_VM(4); }
    else    { WAIT_VM(0); }
    BAR_END;

    // p5: read buf1 A(rows wm*128+0..63) + B(first 32); stage A-h1(ta)->buf0
    READ_A(A1, 0); READ_B(B1, 0);
    if (st) stageA(0, 1, ta);
    BAR_LGK;
    DO_MFMA(0, 0);
    BAR_END;

    // p6: read buf1 B(second 32); stage B-h1(ta)->buf0
    READ_B(B1, 1);
    if (st) stageB(0, 1, ta);
    BAR_LGK;
    DO_MFMA(0, 2);
    BAR_END;

    // p7: read buf1 A(rows wm*128+64..127); stage B-h0(tb)->buf1
    //     [buf1 B fully read by p6's barrier]
    READ_A(A1, 1);
    if (st) stageB(1, 0, tb);
    BAR_LGK;
    DO_MFMA(4, 0);
    BAR_END;

    // p8: no reads; stage A-h0(tb)->buf1 [buf1 A fully read by p7's barrier];
    //     wait tile ta complete: vmcnt(4) retires {B0h0,A0h0,A0h1,B0h1}(ta),
    //     leaves {B1h0,A1h0}(tb) in flight.
    if (st) stageA(1, 0, tb);
    DO_MFMA(4, 2);
    if (st) { WAIT_VM(4); }
    BAR_END;
  }

  // Epilogue. C/D layout: col = lane&15 (n), row = quad*4 + r (m).
  // Row-grouped store order: per row, all 4 column-chunks back-to-back.
  if constexpr (EPI == 0) {
    float bv[4]; int ee[4]; short* op[4];
#pragma unroll
    for (int j = 0; j < 4; ++j) {
      const int n = n0 + wn * 64 + j * 16 + l15;
      bv[j] = bias[n];
      const int which = n >> 10;
      ee[j] = n & 1023;
      op[j] = (which == 0) ? (short*)o0 : ((which == 1) ? (short*)o1 : (short*)o2);
    }
#pragma unroll
    for (int i = 0; i < 8; ++i)
#pragma unroll
      for (int r = 0; r < 4; ++r) {
        const int mloc = m0 + wm * 128 + i * 16 + quad * 4 + r;
        const size_t rowoff = (size_t)mloc * 1024;
#pragma unroll
        for (int j = 0; j < 4; ++j)
          op[j][rowoff + ee[j]] = f2bf(acc[i][j][r] + bv[j]);
      }
  } else {
    float bv[4]; int nn[4];
#pragma unroll
    for (int j = 0; j < 4; ++j) {
      nn[j] = n0 + wn * 64 + j * 16 + l15;
      bv[j] = bias[nn[j]];
    }
#pragma unroll
    for (int i = 0; i < 8; ++i)
#pragma unroll
      for (int r = 0; r < 4; ++r) {
        const int mloc = m0 + wm * 128 + i * 16 + quad * 4 + r;
        const int g = ((mloc >> tsh) << 11) + rowbase + (mloc & ((1 << tsh) - 1));
        const size_t rowoff = (size_t)g * 1024;
#pragma unroll
        for (int j = 0; j < 4; ++j)
          ((float*)o0)[rowoff + nn[j]] = acc[i][j][r] + bv[j];
      }
  }
}

// ---------------------------------------------------------------------------
// Attention: one block (256 thr, 4 waves) per local t'.
// R5: vectorized norms (8 x short8 per row) and 2-thread-per-row softmax
// (8 x short8 per half-row + shfl_xor(1) pair combine). Same numerics.
// ---------------------------------------------------------------------------
__global__ __launch_bounds__(256)
void attn_kernel(const short* __restrict__ qb, const short* __restrict__ kb,
                 const short* __restrict__ vb, short* __restrict__ wsb, int tch) {
  __shared__ __align__(16) char smem[55296];
  short* qs  = (short*)smem;             // [128][72]
  short* ks  = (short*)(smem + 18432);   // [128][72]
  short* Ps  = (short*)smem;             // [128][136] (overlays qs/ks after S)
  short* vt  = (short*)(smem + 36864);   // [64][136]
  float* rsq = (float*)(smem + 54272);   // [128]
  float* rsk = rsq + 128;                // [128]

  const int tp   = blockIdx.x;
  const int tid  = threadIdx.x;
  const int lane = tid & 63, wave = tid >> 6;
  const int l15  = lane & 15, quad = lane >> 4;
  const size_t base = (size_t)tp * 8192;

#pragma unroll
  for (int it = 0; it < 4; it++) {
    const int c = tid + it * 256;
    const int row = c >> 3, c8 = (c & 7) * 8;
    uint4 qv = *(const uint4*)(qb + base + row * 64 + c8);
    uint4 kv = *(const uint4*)(kb + base + row * 64 + c8);
    *(uint4*)(qs + row * 72 + c8) = qv;
    *(uint4*)(ks + row * 72 + c8) = kv;
    short tmp[8];
    *(uint4*)tmp = *(const uint4*)(vb + base + row * 64 + c8);
#pragma unroll
    for (int j = 0; j < 8; j++) vt[(c8 + j) * 136 + row] = tmp[j];
  }
  __syncthreads();

  {
    const short* src = (tid < 128) ? qs : ks;
    const int r = tid & 127;
    const short8* rp = (const short8*)(src + r * 72);
    float s = 0.f;
#pragma unroll
    for (int k8 = 0; k8 < 8; k8++) {
      short8 v = rp[k8];
#pragma unroll
      for (int j = 0; j < 8; j++) { float x = bf2f(v[j]); s += x * x; }
    }
    ((tid < 128) ? rsq : rsk)[r] = rsqrtf(s);
  }
  __syncthreads();

  const int wm = wave >> 1, wn = wave & 1;
  floatx4 acc[4][4] = {};
#pragma unroll
  for (int kk = 0; kk < 64; kk += 32) {
    short8 af[4], bfv[4];
#pragma unroll
    for (int i = 0; i < 4; i++)
      af[i] = *(const short8*)(qs + (wm * 64 + i * 16 + l15) * 72 + kk + quad * 8);
#pragma unroll
    for (int j = 0; j < 4; j++)
      bfv[j] = *(const short8*)(ks + (wn * 64 + j * 16 + l15) * 72 + kk + quad * 8);
#pragma unroll
    for (int i = 0; i < 4; i++)
#pragma unroll
      for (int j = 0; j < 4; j++)
        acc[i][j] = __builtin_amdgcn_mfma_f32_16x16x32_bf16(af[i], bfv[j], acc[i][j], 0, 0, 0);
  }
  __syncthreads();

#pragma unroll
  for (int i = 0; i < 4; i++)
#pragma unroll
    for (int j = 0; j < 4; j++)
#pragma unroll
      for (int r = 0; r < 4; r++) {
        const int a    = wm * 64 + i * 16 + quad * 4 + r;
        const int bcol = wn * 64 + j * 16 + l15;
        Ps[a * 136 + bcol] = f2bf(acc[i][j][r] * rsq[a] * rsk[bcol] * 0.125f);
      }
  __syncthreads();

  {
    const int r = tid >> 1, h = tid & 1;
    short8* rp = (short8*)(Ps + r * 136 + h * 64);
    short8 v[8];
    float mx = -1e30f;
#pragma unroll
    for (int k8 = 0; k8 < 8; k8++) {
      v[k8] = rp[k8];
#pragma unroll
      for (int j = 0; j < 8; j++) mx = fmaxf(mx, bf2f(v[k8][j]));
    }
    mx = fmaxf(mx, __shfl_xor(mx, 1, 64));
    float sum = 0.f;
#pragma unroll
    for (int k8 = 0; k8 < 8; k8++) {
      short8 o;
#pragma unroll
      for (int j = 0; j < 8; j++) {
        float p = __expf(bf2f(v[k8][j]) - mx);
        sum += p;
        o[j] = f2bf(p);
      }
      rp[k8] = o;
    }
    sum += __shfl_xor(sum, 1, 64);
    if (h == 0) rsq[r] = 1.0f / sum;
  }
  __syncthreads();

  floatx4 acc2[2][4] = {};
#pragma unroll
  for (int kb2 = 0; kb2 < 128; kb2 += 32) {
    short8 af[2], bfv[4];
#pragma unroll
    for (int ti = 0; ti < 2; ti++)
      af[ti] = *(const short8*)(Ps + (wave * 32 + ti * 16 + l15) * 136 + kb2 + quad * 8);
#pragma unroll
    for (int tj = 0; tj < 4; tj++)
      bfv[tj] = *(const short8*)(vt + (tj * 16 + l15) * 136 + kb2 + quad * 8);
#pragma unroll
    for (int ti = 0; ti < 2; ti++)
#pragma unroll
      for (int tj = 0; tj < 4; tj++)
        acc2[ti][tj] = __builtin_amdgcn_mfma_f32_16x16x32_bf16(af[ti], bfv[tj], acc2[ti][tj], 0, 0, 0);
  }

#pragma unroll
  for (int ti = 0; ti < 2; ti++)
#pragma unroll
    for (int tj = 0; tj < 4; tj++)
#pragma unroll
      for (int r = 0; r < 4; r++) {
        const int a = wave * 32 + ti * 16 + quad * 4 + r;
        const int d = tj * 16 + l15;
        const float v = acc2[ti][tj][r] * rsq[a];
        const int bz = a >> 4, h = a & 15;
        wsb[((size_t)bz * tch + tp) * 1024 + h * 64 + d] = f2bf(v);
      }
}

// ---------------------------------------------------------------------------
extern "C" void kernel_launch(void* const* d_in, const int* in_sizes, int n_in,
                              void* d_out, int out_size, void* d_ws, size_t ws_size,
                              hipStream_t stream) {
  const float* query = (const float*)d_in[0];
  // d_in[1] (key), d_in[2] (value) unused per reference semantics.
  const float* w_qkv = (const float*)d_in[3];
  const float* b_qkv = (const float*)d_in[4];
  const float* w_out = (const float*)d_in[5];
  const float* b_out = (const float*)d_in[6];
  float* out = (float*)d_out;

  // Chunk count C: footprint = 8.4MB weights + 4*(16384/C)*2048 B.
  // Cap at 64 so Mc stays a multiple of 256 (GEMM tile).
  int C = 64;
  for (int c = 1; c <= 64; c <<= 1) {
    if ((size_t)(8388608 + 134217728 / c) <= ws_size) { C = c; break; }
  }
  const int Mc  = 16384 / C;   // rows per chunk (multiple of 256)
  const int TCH = 2048 / C;    // t's per chunk
  int tsh = 0; while ((1 << tsh) < TCH) tsh++;

  short* wqkvb = (short*)d_ws;            // 3072*1024 bf16
  short* woutb = wqkvb + 3145728;         // 1024*1024 bf16
  short* qbuf  = woutb + 1048576;
  short* kbuf  = qbuf + (size_t)Mc * 1024;
  short* vbuf  = kbuf + (size_t)Mc * 1024;
  short* wsb   = vbuf + (size_t)Mc * 1024;   // overlay: bf16 query chunk, then attn out

  cvt_bf16<<<3145728 / 8 / 256, 256, 0, stream>>>(w_qkv, wqkvb, 3145728 / 8);
  cvt_bf16<<<1048576 / 8 / 256, 256, 0, stream>>>(w_out, woutb, 1048576 / 8);

  for (int c = 0; c < C; c++) {
    const int n8 = Mc * 1024 / 8;
    cvt_bf16<<<(n8 + 255) / 256, 256, 0, stream>>>(query + (size_t)c * Mc * 1024, wsb, n8);
    gemm_bf<0><<<dim3(12, Mc / 256), 512, 0, stream>>>(
        wsb, wqkvb, b_qkv, qbuf, kbuf, vbuf, 1024, 0, 0);
    attn_kernel<<<TCH, 256, 0, stream>>>(qbuf, kbuf, vbuf, wsb, TCH);
    gemm_bf<1><<<dim3(4, Mc / 256), 512, 0, stream>>>(
        wsb, woutb, b_out, out, nullptr, nullptr, 1024, c * TCH, tsh);
  }
}